// Round 1
// baseline (1822.913 us; speedup 1.0000x reference)
//
#include <hip/hip_runtime.h>

#define EPS 1e-5f

static constexpr int D  = 128;
static constexpr int L  = 256;
static constexpr int C  = 256;
static constexpr int OC = 32;
static constexpr int PC = 256;
static constexpr int TLM = 4;   // (l,m) tile: 4x4 pairs per block

// ---------------- Kernel 1: LayerNorm + dual projection ----------------
// grid: (D*L)/8 blocks of 256 threads; 8 rows (d,l) per block.
// Outputs: leftT[l][d][o] = LN(x) @ Wl^T + bl
//          rightT[l][d][o] = (LN(x) @ Wr^T + br) / D
__global__ __launch_bounds__(256)
void ln_proj_kernel(const float* __restrict__ msa,
                    const float* __restrict__ ln_w,
                    const float* __restrict__ ln_b,
                    const float* __restrict__ Wl, const float* __restrict__ bl,
                    const float* __restrict__ Wr, const float* __restrict__ br,
                    float* __restrict__ leftT, float* __restrict__ rightT) {
  __shared__ float xs[8][C];       // 8 KB
  __shared__ float stats[8][2];    // mu, rstd per row

  const int tid = threadIdx.x;
  const int row0 = blockIdx.x * 8;

  // load 8 rows (2048 floats) coalesced as float4
  {
    const float4* src = (const float4*)(msa + (size_t)row0 * C);
    float4* dst = (float4*)(&xs[0][0]);
    dst[tid]       = src[tid];
    dst[tid + 256] = src[tid + 256];
  }
  __syncthreads();

  // per-row stats: 32 threads per row
  {
    const int r = tid >> 5, i = tid & 31;
    float s = 0.f, s2 = 0.f;
    #pragma unroll
    for (int c = i; c < C; c += 32) { float v = xs[r][c]; s += v; s2 += v * v; }
    #pragma unroll
    for (int off = 16; off >= 1; off >>= 1) {
      s  += __shfl_xor(s, off);
      s2 += __shfl_xor(s2, off);
    }
    if (i == 0) {
      float mu  = s * (1.0f / C);
      float var = s2 * (1.0f / C) - mu * mu;
      stats[r][0] = mu;
      stats[r][1] = rsqrtf(var + EPS);
    }
  }
  __syncthreads();

  // normalize in LDS
  for (int v = tid; v < 8 * C; v += 256) {
    const int r = v >> 8, c = v & 255;
    xs[r][c] = (xs[r][c] - stats[r][0]) * stats[r][1] * ln_w[c] + ln_b[c];
  }
  __syncthreads();

  // projections: thread (r = tid>>5, o = tid&31)
  {
    const int r = tid >> 5, o = tid & 31;
    const float4* wl4 = (const float4*)(Wl + o * C);
    const float4* wr4 = (const float4*)(Wr + o * C);
    const float4* x4  = (const float4*)(&xs[r][0]);
    float accl = 0.f, accr = 0.f;
    #pragma unroll
    for (int c4 = 0; c4 < C / 4; ++c4) {
      const float4 xv = x4[c4];
      const float4 wlv = wl4[c4];
      const float4 wrv = wr4[c4];
      accl += xv.x * wlv.x + xv.y * wlv.y + xv.z * wlv.z + xv.w * wlv.w;
      accr += xv.x * wrv.x + xv.y * wrv.y + xv.z * wrv.z + xv.w * wrv.w;
    }
    const int row = row0 + r;          // row = d*L + l
    const int d = row >> 8;            // L == 256
    const int l = row & 255;
    const int oi = (l * D + d) * OC + o;
    leftT[oi]  = accl + bl[o];
    rightT[oi] = (accr + br[o]) * (1.0f / D);
  }
}

// ---------------- Kernel 2: fused outer-product + output projection ----------------
// grid: (L/TLM, L/TLM) = (64,64); block 256 threads.
// Phase 1: O[128][128] = sum_d A[d][ll*32+c] * B[d][mm*32+q]  (K=128 GEMM)
// Phase 2: OUT[pair][p] = sum_k O[pair][k] * Wout[p][k] + bout[p]
__global__ __launch_bounds__(256)
void fused_kernel(const float* __restrict__ leftT,
                  const float* __restrict__ rightT,
                  const float* __restrict__ Wout,
                  const float* __restrict__ bout,
                  float* __restrict__ out) {
  __shared__ float As[16][128];     // 8 KB
  __shared__ float Bs[16][128];     // 8 KB
  __shared__ float Os[16][1024];    // 64 KB  (pair = ll*4+mm, k = c*32+q)
  __shared__ float Ws[PC][36];      // 36 KB  (32-k chunk of Wout, +4 pad, 16B-aligned rows)

  const int tid = threadIdx.x;
  const int l0 = blockIdx.y * TLM;
  const int m0 = blockIdx.x * TLM;
  const float* Abase = leftT  + (size_t)l0 * (D * OC);
  const float* Bbase = rightT + (size_t)m0 * (D * OC);

  const int tx = tid & 15, ty = tid >> 4;  // 16x16 thread grid, 8x8 outputs each

  float acc[8][8];
  #pragma unroll
  for (int i = 0; i < 8; ++i)
    #pragma unroll
    for (int j = 0; j < 8; ++j) acc[i][j] = 0.f;

  // ---- Phase 1: 128x128x128 GEMM ----
  for (int k0 = 0; k0 < D; k0 += 16) {
    #pragma unroll
    for (int it = 0; it < 2; ++it) {
      const int v = it * 256 + tid;      // 0..511 float4 slots
      const int dk = v >> 5;             // 0..15
      const int rem = v & 31;
      const int ll = rem >> 3, c4 = rem & 7;
      const size_t goff = (size_t)ll * (D * OC) + (size_t)(k0 + dk) * OC + c4 * 4;
      *(float4*)(&As[dk][ll * 32 + c4 * 4]) = *(const float4*)(Abase + goff);
      *(float4*)(&Bs[dk][ll * 32 + c4 * 4]) = *(const float4*)(Bbase + goff);
    }
    __syncthreads();
    #pragma unroll
    for (int k = 0; k < 16; ++k) {
      float a[8], b[8];
      *(float4*)(a)     = *(const float4*)(&As[k][ty * 8]);
      *(float4*)(a + 4) = *(const float4*)(&As[k][ty * 8 + 4]);
      *(float4*)(b)     = *(const float4*)(&Bs[k][tx * 8]);
      *(float4*)(b + 4) = *(const float4*)(&Bs[k][tx * 8 + 4]);
      #pragma unroll
      for (int i = 0; i < 8; ++i)
        #pragma unroll
        for (int j = 0; j < 8; ++j)
          acc[i][j] += a[i] * b[j];
    }
    __syncthreads();
  }

  // ---- Phase 1.5: scatter acc -> Os[pair][c*32+q] ----
  {
    const int ss = tx * 8;
    const int mm = ss >> 5, qq = ss & 31;
    #pragma unroll
    for (int i = 0; i < 8; ++i) {
      const int rr = ty * 8 + i;
      const int ll = rr >> 5, cc = rr & 31;
      float* dst = &Os[ll * 4 + mm][cc * 32 + qq];
      *(float4*)(dst)     = *(float4*)(&acc[i][0]);
      *(float4*)(dst + 4) = *(float4*)(&acc[i][4]);
    }
  }
  __syncthreads();

  // ---- Phase 2: OUT[16][256] = Os[16][1024] @ Wout^T, K chunked by 32 ----
  float oacc[16];
  #pragma unroll
  for (int i = 0; i < 16; ++i) oacc[i] = 0.f;
  const int pgrp = tid & 63;   // p = pgrp + 64*i
  const int pq = tid >> 6;     // pairs pq*4 .. pq*4+3 (whole wave same pairs -> LDS broadcast)

  for (int kc = 0; kc < 1024; kc += 32) {
    // stage Ws[p][k] chunk: 256*32 floats = 2048 float4, 8 per thread
    #pragma unroll
    for (int it = 0; it < 8; ++it) {
      const int f = it * 256 + tid;      // float4 id
      const int p = f >> 3, k4 = f & 7;
      *(float4*)(&Ws[p][k4 * 4]) = *(const float4*)(Wout + (size_t)p * 1024 + kc + k4 * 4);
    }
    __syncthreads();
    #pragma unroll
    for (int k = 0; k < 32; k += 4) {
      float4 w[4], os[4];
      #pragma unroll
      for (int i = 0; i < 4; ++i) w[i] = *(const float4*)(&Ws[pgrp + 64 * i][k]);
      #pragma unroll
      for (int j = 0; j < 4; ++j) os[j] = *(const float4*)(&Os[pq * 4 + j][kc + k]);
      #pragma unroll
      for (int j = 0; j < 4; ++j)
        #pragma unroll
        for (int i = 0; i < 4; ++i)
          oacc[j * 4 + i] += os[j].x * w[i].x + os[j].y * w[i].y
                           + os[j].z * w[i].z + os[j].w * w[i].w;
    }
    __syncthreads();
  }

  // ---- epilogue ----
  #pragma unroll
  for (int j = 0; j < 4; ++j) {
    const int pair = pq * 4 + j;
    const int ll = pair >> 2, mm = pair & 3;
    const size_t base = ((size_t)(l0 + ll) * L + (m0 + mm)) * PC;
    #pragma unroll
    for (int i = 0; i < 4; ++i) {
      const int p = pgrp + 64 * i;
      out[base + p] = oacc[j * 4 + i] + bout[p];
    }
  }
}

extern "C" void kernel_launch(void* const* d_in, const int* in_sizes, int n_in,
                              void* d_out, int out_size, void* d_ws, size_t ws_size,
                              hipStream_t stream) {
  const float* msa  = (const float*)d_in[0];
  const float* ln_w = (const float*)d_in[1];
  const float* ln_b = (const float*)d_in[2];
  const float* Wl   = (const float*)d_in[3];
  const float* bl   = (const float*)d_in[4];
  const float* Wr   = (const float*)d_in[5];
  const float* br   = (const float*)d_in[6];
  const float* Wout = (const float*)d_in[7];
  const float* bout = (const float*)d_in[8];
  float* out = (float*)d_out;

  float* leftT  = (float*)d_ws;                       // [L][D][OC] = 4 MB
  float* rightT = leftT + (size_t)L * D * OC;         // [L][D][OC] = 4 MB

  ln_proj_kernel<<<dim3((D * L) / 8), 256, 0, stream>>>(
      msa, ln_w, ln_b, Wl, bl, Wr, br, leftT, rightT);
  fused_kernel<<<dim3(L / TLM, L / TLM), 256, 0, stream>>>(
      leftT, rightT, Wout, bout, out);
}

// Round 3
// 474.927 us; speedup vs baseline: 3.8383x; 3.8383x over previous
//
#include <hip/hip_runtime.h>

#define EPS 1e-5f

static constexpr int D  = 128;
static constexpr int L  = 256;
static constexpr int C  = 256;
static constexpr int OC = 32;
static constexpr int PC = 256;

typedef __attribute__((ext_vector_type(8))) short bfrag8;   // 8 bf16 (4 VGPR)
typedef __attribute__((ext_vector_type(4))) short bhalf4;   // 4 bf16 (8B)
typedef __attribute__((ext_vector_type(4))) float f32x4;

__device__ inline unsigned short f2bf(float f) {
  union { float f; unsigned u; } v; v.f = f;
  unsigned r = v.u + 0x7FFF + ((v.u >> 16) & 1);   // RNE
  return (unsigned short)(r >> 16);
}

// ---------------- Kernel 0: Wout fp32 -> bf16, k reordered (q*32+c) ----------------
__global__ __launch_bounds__(256)
void prep_wout(const float* __restrict__ Wout, unsigned short* __restrict__ Wbf) {
  const int p = blockIdx.x, t = threadIdx.x;
  #pragma unroll
  for (int i = 0; i < 4; ++i) {
    const int kn = i * 256 + t;          // new k = q*32 + c
    const int cc = kn & 31, qq = kn >> 5;
    Wbf[p * 1024 + kn] = f2bf(Wout[p * 1024 + cc * 32 + qq]);
  }
}

// ---------------- Kernel 1: LayerNorm + dual projection -> bf16 K-major ----------------
// block = (l, d0-group of 8 d's); outputs leftT[(l*32+o)*128 + d], rightT likewise (/D folded)
__global__ __launch_bounds__(256)
void ln_proj(const float* __restrict__ msa,
             const float* __restrict__ ln_w, const float* __restrict__ ln_b,
             const float* __restrict__ Wl, const float* __restrict__ bl,
             const float* __restrict__ Wr, const float* __restrict__ br,
             unsigned short* __restrict__ leftT, unsigned short* __restrict__ rightT) {
  __shared__ float xs[8][C];
  __shared__ float stats[8][2];
  __shared__ float lo[32][9], ro[32][9];   // +1 pad -> conflict-free transpose reads

  const int t = threadIdx.x;
  const int l = blockIdx.x, d0 = blockIdx.y * 8;

  { // load 8 rows (d0..d0+7, fixed l), coalesced float4 per row
    const int r = t >> 5, i = t & 31;
    const float4* src = (const float4*)(msa + ((size_t)(d0 + r) * L + l) * C);
    float4* dst = (float4*)&xs[r][0];
    dst[i]      = src[i];
    dst[i + 32] = src[i + 32];
  }
  __syncthreads();

  { // stats: 32 threads per row
    const int r = t >> 5, i = t & 31;
    float s = 0.f, s2 = 0.f;
    #pragma unroll
    for (int c = i; c < C; c += 32) { float v = xs[r][c]; s += v; s2 += v * v; }
    #pragma unroll
    for (int off = 16; off >= 1; off >>= 1) {
      s  += __shfl_xor(s, off);
      s2 += __shfl_xor(s2, off);
    }
    if (i == 0) {
      float mu  = s * (1.0f / C);
      float var = s2 * (1.0f / C) - mu * mu;
      stats[r][0] = mu;
      stats[r][1] = rsqrtf(var + EPS);
    }
  }
  __syncthreads();

  for (int v = t; v < 8 * C; v += 256) {
    const int r = v >> 8, c = v & 255;
    xs[r][c] = (xs[r][c] - stats[r][0]) * stats[r][1] * ln_w[c] + ln_b[c];
  }
  __syncthreads();

  { // projections
    const int r = t >> 5, o = t & 31;
    const float4* wl4 = (const float4*)(Wl + o * C);
    const float4* wr4 = (const float4*)(Wr + o * C);
    const float4* x4  = (const float4*)(&xs[r][0]);
    float accl = 0.f, accr = 0.f;
    #pragma unroll
    for (int c4 = 0; c4 < C / 4; ++c4) {
      const float4 xv = x4[c4], wlv = wl4[c4], wrv = wr4[c4];
      accl += xv.x * wlv.x + xv.y * wlv.y + xv.z * wlv.z + xv.w * wlv.w;
      accr += xv.x * wrv.x + xv.y * wrv.y + xv.z * wrv.z + xv.w * wrv.w;
    }
    lo[o][r] = accl + bl[o];
    ro[o][r] = (accr + br[o]) * (1.0f / D);
  }
  __syncthreads();

  if (t < 64) { // transpose + bf16x8 16B stores
    const int o = t & 31;
    const float (*src)[9] = (t < 32) ? lo : ro;
    unsigned short* dst = (t < 32) ? leftT : rightT;
    unsigned short tmp[8];
    #pragma unroll
    for (int r = 0; r < 8; ++r) tmp[r] = f2bf(src[o][r]);
    *(bfrag8*)(dst + ((size_t)l * 32 + o) * 128 + d0) = *(bfrag8*)tmp;
  }
}

// ---------------- Kernel 2: fused outer-product + output projection (MFMA) ----------------
// grid 4096 (XCD-swizzled -> 64x64 lm-tiles), 256 threads = 4 waves.
__global__ __launch_bounds__(256)
void fused_mfma(const unsigned short* __restrict__ leftT,
                const unsigned short* __restrict__ rightT,
                const unsigned short* __restrict__ Wbf,
                const float* __restrict__ bout,
                float* __restrict__ out) {
  __shared__ char smem[32768];   // phase1: A[16K]+B[16K] (k-half); phase2: Os[16][1024] bf16

  const int flat = blockIdx.x;
  const int wg = (flat & 7) * 512 + (flat >> 3);   // bijective XCD swizzle (4096 % 8 == 0)
  const int bx = wg & 63, by = wg >> 6;
  const int l0 = by * 4, m0 = bx * 4;

  const char* Aslab = (const char*)(leftT  + (size_t)l0 * 32 * 128);  // 32 KB contiguous
  const char* Bslab = (const char*)(rightT + (size_t)m0 * 32 * 128);

  const int tid = threadIdx.x;
  const int lane = tid & 63, w = tid >> 6;
  const int rh = w >> 1, ch = w & 1;        // wave's row/col half of the 128x128 tile

  f32x4 acc[4][4];
  #pragma unroll
  for (int i = 0; i < 4; ++i)
    #pragma unroll
    for (int j = 0; j < 4; ++j) acc[i][j] = (f32x4)0.f;

  // ---- Phase 1: O[128][128] = A(128xK) * B(KxN), K=128 in two 64-halves ----
  for (int kh = 0; kh < 2; ++kh) {
    // stage 16KB A + 16KB B, global_load_lds w=16, pre-swizzled source (m173)
    #pragma unroll
    for (int i = 0; i < 4; ++i) {
      const int chunk = (w * 4 + i) * 1024;
      const int lb = chunk + lane * 16;            // linear LDS byte
      const int row = lb >> 7;                     // 128B rows (64 bf16 of k)
      const int byte = (lb & 127) ^ ((row & 7) << 4);
      const size_t src = (size_t)row * 256 + kh * 128 + byte;
      __builtin_amdgcn_global_load_lds((const void*)(Aslab + src), (void*)&smem[chunk], 16, 0, 0);
      __builtin_amdgcn_global_load_lds((const void*)(Bslab + src), (void*)&smem[16384 + chunk], 16, 0, 0);
    }
    __syncthreads();

    #pragma unroll
    for (int ks = 0; ks < 2; ++ks) {
      const int kbyte = ks * 64 + ((lane >> 4) << 4);
      bfrag8 a[4], b[4];
      #pragma unroll
      for (int i = 0; i < 4; ++i) {
        const int row = (rh * 4 + i) * 16 + (lane & 15);
        a[i] = *(const bfrag8*)&smem[(row << 7) + (kbyte ^ ((row & 7) << 4))];
      }
      #pragma unroll
      for (int j = 0; j < 4; ++j) {
        const int row = (ch * 4 + j) * 16 + (lane & 15);
        b[j] = *(const bfrag8*)&smem[16384 + (row << 7) + (kbyte ^ ((row & 7) << 4))];
      }
      #pragma unroll
      for (int i = 0; i < 4; ++i)
        #pragma unroll
        for (int j = 0; j < 4; ++j)
          acc[i][j] = __builtin_amdgcn_mfma_f32_16x16x32_bf16(a[i], b[j], acc[i][j], 0, 0, 0);
    }
    __syncthreads();   // guards restage / Os overwrite
  }

  // ---- Phase 1.5: acc -> Os[pair][k=q*32+c] bf16, XOR-swizzled, b64 writes ----
  {
    #pragma unroll
    for (int i = 0; i < 4; ++i) {
      const int row = (rh * 4 + i) * 16 + ((lane >> 4) << 2);  // +reg -> 4 consecutive c
      const int ll = row >> 5, cc = row & 31;
      #pragma unroll
      for (int j = 0; j < 4; ++j) {
        const int col = (ch * 4 + j) * 16 + (lane & 15);
        const int mm = col >> 5, q = col & 31;
        const int pair = ll * 4 + mm;
        const int k = q * 32 + cc;
        unsigned short tmp[4];
        #pragma unroll
        for (int r = 0; r < 4; ++r) tmp[r] = f2bf(acc[i][j][r]);
        const int byte = (pair * 2048) + ((k * 2) ^ ((pair & 7) << 4));
        *(bhalf4*)&smem[byte] = *(bhalf4*)tmp;
      }
    }
  }
  __syncthreads();

  // ---- Phase 2: OUT[16][256] = Os[16][1024] @ WbfT; A from LDS, B from L2 ----
  f32x4 oacc[4];
  #pragma unroll
  for (int j = 0; j < 4; ++j) oacc[j] = (f32x4)0.f;

  const int p0w = w * 64;
  size_t wb[4];
  #pragma unroll
  for (int j = 0; j < 4; ++j)
    wb[j] = (size_t)(p0w + j * 16 + (lane & 15)) * 1024 + ((lane >> 4) * 8);

  #pragma unroll 2
  for (int kc = 0; kc < 1024; kc += 32) {
    const bfrag8 af = *(const bfrag8*)&smem[((lane & 15) * 2048) +
                        ((kc * 2 + ((lane >> 4) << 4)) ^ ((lane & 7) << 4))];
    bfrag8 bf[4];
    #pragma unroll
    for (int j = 0; j < 4; ++j)
      bf[j] = *(const bfrag8*)(Wbf + wb[j] + kc);
    #pragma unroll
    for (int j = 0; j < 4; ++j)
      oacc[j] = __builtin_amdgcn_mfma_f32_16x16x32_bf16(af, bf[j], oacc[j], 0, 0, 0);
  }

  // ---- epilogue ----
  {
    const int pairbase = (lane >> 4) * 4;
    #pragma unroll
    for (int j = 0; j < 4; ++j) {
      const int p = p0w + j * 16 + (lane & 15);
      const float bb = bout[p];
      #pragma unroll
      for (int r = 0; r < 4; ++r) {
        const int pair = pairbase + r;
        const int ll = pair >> 2, mm = pair & 3;
        out[((size_t)(l0 + ll) * L + (m0 + mm)) * PC + p] = oacc[j][r] + bb;
      }
    }
  }
}

extern "C" void kernel_launch(void* const* d_in, const int* in_sizes, int n_in,
                              void* d_out, int out_size, void* d_ws, size_t ws_size,
                              hipStream_t stream) {
  const float* msa  = (const float*)d_in[0];
  const float* ln_w = (const float*)d_in[1];
  const float* ln_b = (const float*)d_in[2];
  const float* Wl   = (const float*)d_in[3];
  const float* bl   = (const float*)d_in[4];
  const float* Wr   = (const float*)d_in[5];
  const float* br   = (const float*)d_in[6];
  const float* Wout = (const float*)d_in[7];
  const float* bout = (const float*)d_in[8];
  float* out = (float*)d_out;

  unsigned short* leftT  = (unsigned short*)d_ws;                 // [L*32][128] bf16 = 2 MB
  unsigned short* rightT = leftT + (size_t)L * 32 * 128;          // 2 MB
  unsigned short* Wbf    = rightT + (size_t)L * 32 * 128;         // [256][1024] bf16 = 512 KB

  prep_wout<<<dim3(PC), 256, 0, stream>>>(Wout, Wbf);
  ln_proj<<<dim3(L, D / 8), 256, 0, stream>>>(msa, ln_w, ln_b, Wl, bl, Wr, br, leftT, rightT);
  fused_mfma<<<dim3(4096), 256, 0, stream>>>(leftT, rightT, Wbf, bout, out);
}

// Round 4
// 130.276 us; speedup vs baseline: 13.9927x; 3.6455x over previous
//
#include <hip/hip_runtime.h>

#define EPS 1e-5f

static constexpr int D  = 128;
static constexpr int L  = 256;
static constexpr int C  = 256;
static constexpr int OC = 32;
static constexpr int PC = 256;

typedef __attribute__((ext_vector_type(8))) short bfrag8;   // 8 bf16 (4 VGPR)
typedef __attribute__((ext_vector_type(4))) short bhalf4;   // 4 bf16 (8B)
typedef __attribute__((ext_vector_type(4))) float f32x4;

__device__ inline unsigned short f2bf(float f) {
  union { float f; unsigned u; } v; v.f = f;
  unsigned r = v.u + 0x7FFF + ((v.u >> 16) & 1);   // RNE
  return (unsigned short)(r >> 16);
}

// ---------------- Kernel 0: prep ----------------
// Wbf3: Wout bf16 packed in MFMA B-fragment order.
//   frag (pf, ks): elem ((pf*32+ks)*64 + lane)*8 + j  holds
//   Wout[p = pf*16 + (lane&15)][orig(k')] with k' = ks*32 + (lane>>4)*8 + j,
//   k' = q*32+c  ->  orig = c*32+q.
// WT[c][64]: [Wl^T | Wr^T] fp32 for ln_proj coalesced reads.
__global__ __launch_bounds__(256)
void prep(const float* __restrict__ Wl, const float* __restrict__ Wr,
          const float* __restrict__ Wout,
          unsigned short* __restrict__ Wbf3, float* __restrict__ WT) {
  const int t = threadIdx.x, b = blockIdx.x;
  {
    const int e0 = (b * 256 + t) * 4;
    const int lane = (e0 >> 3) & 63, ks = (e0 >> 9) & 31, pf = e0 >> 14;
    const int p = pf * 16 + (lane & 15);
    unsigned short v[4];
    #pragma unroll
    for (int j = 0; j < 4; ++j) {
      const int kp = ks * 32 + ((lane >> 4) * 8) + ((e0 + j) & 7);
      const int c = kp & 31, q = kp >> 5;
      v[j] = f2bf(Wout[p * 1024 + c * 32 + q]);
    }
    *(bhalf4*)(Wbf3 + e0) = *(bhalf4*)v;
  }
  if (b < 64) {
    const int e = b * 256 + t;
    const int c = e >> 6, col = e & 63;
    WT[c * 64 + col] = (col < 32) ? Wl[col * 256 + c] : Wr[(col - 32) * 256 + c];
  }
}

// ---------------- Kernel 1: LayerNorm + dual projection -> bf16 K-major ----------------
// 1024 blocks x 256 thr; block = 32 consecutive rows (fixed d, 32 l's).
// leftT[(l*32+o)*128 + d], rightT likewise (/D folded).
__global__ __launch_bounds__(256)
void ln_proj(const float* __restrict__ msa,
             const float* __restrict__ lnw, const float* __restrict__ lnb,
             const float* __restrict__ WT,
             const float* __restrict__ bl, const float* __restrict__ br,
             unsigned short* __restrict__ leftT, unsigned short* __restrict__ rightT) {
  __shared__ float xs[32][260];     // +4 pad: row-stride 260 -> bank spread
  __shared__ float stats[32][2];

  const int t = threadIdx.x;
  const int R0 = blockIdx.x * 32;

  { // load 32 rows x 1KB, fully coalesced
    const float4* src = (const float4*)(msa + (size_t)R0 * C);
    #pragma unroll
    for (int i = 0; i < 8; ++i) {
      const int e = i * 256 + t;          // float4 id
      const int r = e >> 6, c4 = e & 63;
      *(float4*)&xs[r][c4 * 4] = src[e];
    }
  }
  __syncthreads();

  { // stats: 8 lanes per row
    const int r = t >> 3, i = t & 7;
    float s = 0.f, s2 = 0.f;
    #pragma unroll
    for (int c = i; c < C; c += 8) { const float v = xs[r][c]; s += v; s2 += v * v; }
    #pragma unroll
    for (int off = 4; off >= 1; off >>= 1) {
      s  += __shfl_xor(s, off);
      s2 += __shfl_xor(s2, off);
    }
    if (i == 0) {
      const float mu  = s * (1.0f / C);
      const float var = s2 * (1.0f / C) - mu * mu;
      stats[r][0] = mu;
      stats[r][1] = rsqrtf(var + EPS);
    }
  }
  __syncthreads();

  { // normalize in place
    const int r = t >> 3, c0 = (t & 7) * 32;
    const float mu = stats[r][0], rs = stats[r][1];
    #pragma unroll
    for (int j = 0; j < 32; j += 4) {
      float4 v = *(float4*)&xs[r][c0 + j];
      const float4 w  = *(const float4*)&lnw[c0 + j];
      const float4 bb = *(const float4*)&lnb[c0 + j];
      v.x = (v.x - mu) * rs * w.x + bb.x;
      v.y = (v.y - mu) * rs * w.y + bb.y;
      v.z = (v.z - mu) * rs * w.z + bb.z;
      v.w = (v.w - mu) * rs * w.w + bb.w;
      *(float4*)&xs[r][c0 + j] = v;
    }
  }
  __syncthreads();

  { // projection: thread (rr = rows rr, rr+16; u = o-quad)
    const int rr = t >> 4, u = t & 15;
    float4 a0 = {0.f, 0.f, 0.f, 0.f}, a1 = {0.f, 0.f, 0.f, 0.f};
    #pragma unroll 4
    for (int c = 0; c < C; ++c) {
      const float4 w = *(const float4*)&WT[c * 64 + u * 4];   // 16 lanes -> 256B
      const float x0 = xs[rr][c], x1 = xs[rr + 16][c];
      a0.x += w.x * x0; a0.y += w.y * x0; a0.z += w.z * x0; a0.w += w.w * x0;
      a1.x += w.x * x1; a1.y += w.y * x1; a1.z += w.z * x1; a1.w += w.w * x1;
    }
    const int side = u >> 3, ob = (u & 7) * 4;
    const float* bias = side ? br : bl;
    const float sc = side ? (1.0f / D) : 1.0f;
    unsigned short* dst = side ? rightT : leftT;
    const int d = R0 >> 8, lb2 = R0 & 255;
    #pragma unroll
    for (int j = 0; j < 4; ++j) {
      const float bv = bias[ob + j];
      const float v0 = (((const float*)&a0)[j] + bv) * sc;
      const float v1 = (((const float*)&a1)[j] + bv) * sc;
      dst[((size_t)(lb2 + rr)      * 32 + ob + j) * 128 + d] = f2bf(v0);
      dst[((size_t)(lb2 + rr + 16) * 32 + ob + j) * 128 + d] = f2bf(v1);
    }
  }
}

// ---------------- Kernel 2: fused outer-product + output projection ----------------
// 2048 blocks (XCD-swizzled; tile = 8 l x 4 m), 512 thr = 8 waves.
// Phase 1: O[256][128] = A(256xK=128) * B(128xK)^T  (MFMA, LDS-staged, swizzled)
// Phase 2: OUT[32 pairs][256 p] = Os[32][1024] @ Wbf3; B-frags coalesced from global.
__global__ __launch_bounds__(512, 4)
void fused_mfma(const unsigned short* __restrict__ leftT,
                const unsigned short* __restrict__ rightT,
                const unsigned short* __restrict__ Wbf3,
                const float* __restrict__ bout,
                float* __restrict__ out) {
  __shared__ char smem[65536];   // phase1: A@0 (32K) + B@32768 (16K); phase2: Os@0 (64K)

  const int flat = blockIdx.x;
  const int wg = (flat & 7) * 256 + (flat >> 3);   // bijective XCD swizzle (2048%8==0)
  const int mt = wg & 63, lt = wg >> 6;
  const int l0 = lt * 8, m0 = mt * 4;

  const char* Aslab = (const char*)(leftT  + (size_t)l0 * 32 * 128);  // 256 rows x 256B
  const char* Bslab = (const char*)(rightT + (size_t)m0 * 32 * 128);  // 128 rows x 256B

  const int tid = threadIdx.x;
  const int lane = tid & 63, w = tid >> 6;
  const int wr = w >> 1, wc = w & 1;   // wave tile: 64 rows x 64 cols

  f32x4 acc[4][4];
  #pragma unroll
  for (int i = 0; i < 4; ++i)
    #pragma unroll
    for (int j = 0; j < 4; ++j) acc[i][j] = (f32x4)0.f;

  // ---- Phase 1: K=128 in two 64-halves, single-buffered ----
  for (int kh = 0; kh < 2; ++kh) {
    #pragma unroll
    for (int i = 0; i < 4; ++i) {      // A: 32KB
      const int lb = (i * 8 + w) * 1024 + lane * 16;
      const int row = lb >> 7;
      const int sb = (lb & 127) ^ ((row & 7) << 4);
      __builtin_amdgcn_global_load_lds((const void*)(Aslab + (size_t)row * 256 + kh * 128 + sb),
                                       (void*)&smem[(i * 8 + w) * 1024], 16, 0, 0);
    }
    #pragma unroll
    for (int i = 0; i < 2; ++i) {      // B: 16KB
      const int lb = (i * 8 + w) * 1024 + lane * 16;
      const int row = lb >> 7;
      const int sb = (lb & 127) ^ ((row & 7) << 4);
      __builtin_amdgcn_global_load_lds((const void*)(Bslab + (size_t)row * 256 + kh * 128 + sb),
                                       (void*)&smem[32768 + (i * 8 + w) * 1024], 16, 0, 0);
    }
    __syncthreads();

    #pragma unroll
    for (int ks = 0; ks < 2; ++ks) {
      const int kb = ks * 64 + ((lane >> 4) << 4);
      bfrag8 a[4], b[4];
      #pragma unroll
      for (int i = 0; i < 4; ++i) {
        const int row = wr * 64 + i * 16 + (lane & 15);
        a[i] = *(const bfrag8*)&smem[(row << 7) + (kb ^ ((row & 7) << 4))];
      }
      #pragma unroll
      for (int j = 0; j < 4; ++j) {
        const int row = wc * 64 + j * 16 + (lane & 15);
        b[j] = *(const bfrag8*)&smem[32768 + (row << 7) + (kb ^ ((row & 7) << 4))];
      }
      #pragma unroll
      for (int i = 0; i < 4; ++i)
        #pragma unroll
        for (int j = 0; j < 4; ++j)
          acc[i][j] = __builtin_amdgcn_mfma_f32_16x16x32_bf16(a[i], b[j], acc[i][j], 0, 0, 0);
    }
    __syncthreads();   // phase-1 reads done -> safe to restage / write Os
  }

  // ---- Phase 1.5: acc -> Os[pair][k'=q*32+c] bf16 @0, XOR-swizzled ----
  {
    #pragma unroll
    for (int i = 0; i < 4; ++i) {
      const int rowb = wr * 64 + i * 16 + ((lane >> 4) << 2);
      const int ll = rowb >> 5, cc = rowb & 31;
      #pragma unroll
      for (int j = 0; j < 4; ++j) {
        const int col = wc * 64 + j * 16 + (lane & 15);
        const int mm = col >> 5, q = col & 31;
        const int pair = ll * 4 + mm;
        const int kp = q * 32 + cc;
        unsigned short v[4];
        #pragma unroll
        for (int r = 0; r < 4; ++r) v[r] = f2bf(acc[i][j][r]);
        *(bhalf4*)&smem[pair * 2048 + ((kp * 2) ^ ((pair & 7) << 4))] = *(bhalf4*)v;
      }
    }
  }
  __syncthreads();

  // ---- Phase 2: 32x256xK=1024; A from Os (LDS), B coalesced from Wbf3 ----
  f32x4 acc2[2][2];
  #pragma unroll
  for (int i = 0; i < 2; ++i)
    #pragma unroll
    for (int j = 0; j < 2; ++j) acc2[i][j] = (f32x4)0.f;

  const unsigned short* Bw0 = Wbf3 + (((size_t)(2 * w)     * 32) * 64 + lane) * 8;
  const unsigned short* Bw1 = Wbf3 + (((size_t)(2 * w + 1) * 32) * 64 + lane) * 8;

  #pragma unroll 4
  for (int ks = 0; ks < 32; ++ks) {
    bfrag8 a2[2], b2[2];
    #pragma unroll
    for (int rf = 0; rf < 2; ++rf) {
      const int pair = rf * 16 + (lane & 15);
      a2[rf] = *(const bfrag8*)&smem[pair * 2048 +
                 ((ks * 64 + ((lane >> 4) << 4)) ^ ((pair & 7) << 4))];
    }
    b2[0] = *(const bfrag8*)(Bw0 + (size_t)ks * 512);
    b2[1] = *(const bfrag8*)(Bw1 + (size_t)ks * 512);
    #pragma unroll
    for (int rf = 0; rf < 2; ++rf)
      #pragma unroll
      for (int cf = 0; cf < 2; ++cf)
        acc2[rf][cf] = __builtin_amdgcn_mfma_f32_16x16x32_bf16(a2[rf], b2[cf], acc2[rf][cf], 0, 0, 0);
  }

  // ---- epilogue ----
  {
    #pragma unroll
    for (int cf = 0; cf < 2; ++cf) {
      const int p = w * 32 + cf * 16 + (lane & 15);
      const float bb = bout[p];
      #pragma unroll
      for (int rf = 0; rf < 2; ++rf) {
        #pragma unroll
        for (int r = 0; r < 4; ++r) {
          const int pair = rf * 16 + ((lane >> 4) << 2) + r;
          const int ll = pair >> 2, mm = pair & 3;
          out[((size_t)(l0 + ll) * L + (m0 + mm)) * PC + p] = acc2[rf][cf][r] + bb;
        }
      }
    }
  }
}

extern "C" void kernel_launch(void* const* d_in, const int* in_sizes, int n_in,
                              void* d_out, int out_size, void* d_ws, size_t ws_size,
                              hipStream_t stream) {
  const float* msa  = (const float*)d_in[0];
  const float* ln_w = (const float*)d_in[1];
  const float* ln_b = (const float*)d_in[2];
  const float* Wl   = (const float*)d_in[3];
  const float* bl   = (const float*)d_in[4];
  const float* Wr   = (const float*)d_in[5];
  const float* br   = (const float*)d_in[6];
  const float* Wout = (const float*)d_in[7];
  const float* bout = (const float*)d_in[8];
  float* out = (float*)d_out;

  unsigned short* leftT  = (unsigned short*)d_ws;                 // [L*32][128] bf16 = 2 MB
  unsigned short* rightT = leftT + (size_t)L * 32 * 128;          // 2 MB
  unsigned short* Wbf3   = rightT + (size_t)L * 32 * 128;         // 512 KB, frag-packed
  float* WT              = (float*)(Wbf3 + (size_t)PC * 1024);    // [256][64] fp32 = 64 KB

  prep<<<dim3(256), 256, 0, stream>>>(Wl, Wr, Wout, Wbf3, WT);
  ln_proj<<<dim3((D * L) / 32), 256, 0, stream>>>(msa, ln_w, ln_b, WT, bl, br, leftT, rightT);
  fused_mfma<<<dim3(2048), 512, 0, stream>>>(leftT, rightT, Wbf3, bout, out);
}